// Round 7
// baseline (476.148 us; speedup 1.0000x reference)
//
#include <hip/hip_runtime.h>

// LocalRefinedAttention round 7 = round 6 + persistent blocks + SW pipeline.
// Round 6 post-mortem: per-block startup chain (~6-8K cyc) paid 18x per CU
// with only ~2.4 blocks resident -> latency-bound. Fix: grid 1152 all-resident,
// 4 patch-pairs per block (XCD-contiguous, jb-adjacent iterations -> L1 reuse),
// X prefetched for it+1 during phase4, weights re-read from L1 per iteration
// in pinned sub-clusters. __launch_bounds__(256,4) for 4 blocks/CU.
//
// B=4, C=64, H=W=192, PS=8, STRIDE=4, PAD=2, NHEADS=4, head_dim=16.
// token t = channel; feature/spatial s = pi*8+pj; h = 4*ib+pi-2, w = 4*jb+pj-2.
// Parity planes: p = (pi>=4)*2 + (pj>=4); plane[p][b][ch][h][w2=196] at w2=w+2.
// Each (pixel, p) has exactly one writing patch -> no atomics, no memset.

typedef _Float16 f16;
typedef _Float16 f16x4 __attribute__((ext_vector_type(4)));
typedef _Float16 f16x8 __attribute__((ext_vector_type(8)));
typedef float    f32x4 __attribute__((ext_vector_type(4)));

#define NHP 48
#define LPB (NHP * NHP)          // 2304
#define NPATCH (4 * LPB)         // 9216
#define NPID2 (NPATCH / 2)       // 4608 patch-pairs
#define ITERS 4
#define GRID (NPID2 / ITERS)     // 1152 blocks: 144/XCD, ~4.5/CU, all-resident
#define PLELEM (256 * 192 * 196) // f16 elements per parity plane
#define WS_NEED (32768ull + 4ull * PLELEM * 2ull)

#define MFMA32(A, B, C) __builtin_amdgcn_mfma_f32_16x16x32_f16((A), (B), (C), 0, 0, 0)
#define MFMA16(A, B, C) __builtin_amdgcn_mfma_f32_16x16x16f16((A), (B), (C), 0, 0, 0)

static __device__ __forceinline__ f16x4 pack4(f32x4 a) {
    f16x4 r;
    r[0] = (f16)a[0]; r[1] = (f16)a[1]; r[2] = (f16)a[2]; r[3] = (f16)a[3];
    return r;
}

// ---- weights fp32 -> f16 row-major; SCALE*log2(e) folded into Wq ----
__global__ __launch_bounds__(256) void wcvt_kernel(
    const float* __restrict__ wq, const float* __restrict__ wk,
    const float* __restrict__ wv, const float* __restrict__ wp,
    f16* __restrict__ wh)
{
    const int idx = blockIdx.x * 256 + threadIdx.x;   // 0..16383
    const int m = idx >> 12;
    const int r = idx & 4095;
    const float* src = (m == 0) ? wq : (m == 1) ? wk : (m == 2) ? wv : wp;
    const float s = (m == 0) ? 0.36067376022224085f : 1.0f;  // 0.25 * log2(e)
    wh[idx] = (f16)(src[r] * s);
}

static __device__ __forceinline__ void calc_coords(
    int pid2, int* bA, int* jbA, int* r0A, int* c0A)
{
    #pragma unroll
    for (int u = 0; u < 2; ++u) {
        const int pid = pid2 * 2 + u;
        const int b   = pid / LPB;
        const int rem = pid - b * LPB;
        const int ib  = rem / NHP;
        const int jb  = rem - ib * NHP;
        bA[u]  = b;
        jbA[u] = jb;
        r0A[u] = ib * 4 - 2;
        c0A[u] = jb * 4 - 2;
    }
}

static __device__ __forceinline__ void load_x(
    const float* __restrict__ x, float2 xr[2][2][4],
    const int* bA, const int* r0A, const int* c0A, int ch)
{
    #pragma unroll
    for (int u = 0; u < 2; ++u) {
        const float* xb = x + ((size_t)(bA[u] * 64 + ch) * 192) * 192;
        #pragma unroll
        for (int kt = 0; kt < 2; ++kt) {
            const int lg = ch; // unused; silence
            (void)lg;
            const int rr = r0A[u] + kt * 4 + (threadIdx.x >> 4 & 3);
            const int rc = (rr >= 0 && rr < 192) ? rr : 0;
            const float* src = xb + (size_t)rc * 192;
            #pragma unroll
            for (int q2 = 0; q2 < 4; ++q2) {
                int col = c0A[u] + 2 * q2;
                col = (col < 0) ? 0 : ((col > 190) ? 190 : col);
                xr[u][kt][q2] = *(const float2*)(src + col);
            }
        }
    }
}

template <bool USE_PLANES>
__global__ __launch_bounds__(256, 4) void patch_attn_kernel(
    const float* __restrict__ x, const f16* __restrict__ wh,
    f16* __restrict__ planes, float* __restrict__ out)
{
    // Packed LDS per patch: Kp[d>>2][key][d&3], Vp[key>>2][d][key&3] (8 KB each)
    __shared__ f16 Kp[2][4096];
    __shared__ f16 Vp[2][4096];

    const int tid  = threadIdx.x;
    const int wv_  = tid >> 6;
    const int lane = tid & 63;
    const int lr   = lane & 15;
    const int lg   = lane >> 4;
    const int chL  = wv_ * 16 + lr;          // this thread's token/channel row

    // Persistent mapping: XCD n&7 owns pid2 range [xcd*576, xcd*576+576);
    // block slot n>>3 takes 4 consecutive pid2 -> iterations are jb-adjacent.
    const int n    = blockIdx.x;
    const int base = (n & 7) * (NPID2 / 8) + (n >> 3) * ITERS;

    const f32x4 Z = (f32x4){0.f, 0.f, 0.f, 0.f};

    int bA[2], jbA[2], r0A[2], c0A[2];
    calc_coords(base, bA, jbA, r0A, c0A);

    // Pre-loop X load for it=0 (exposed once per block).
    float2 xr[2][2][4];
    #pragma unroll
    for (int u = 0; u < 2; ++u) {
        const float* xb = x + ((size_t)(bA[u] * 64 + chL) * 192) * 192;
        #pragma unroll
        for (int kt = 0; kt < 2; ++kt) {
            const int rr = r0A[u] + kt * 4 + lg;
            const int rc = (rr >= 0 && rr < 192) ? rr : 0;
            const float* src = xb + (size_t)rc * 192;
            #pragma unroll
            for (int q2 = 0; q2 < 4; ++q2) {
                int col = c0A[u] + 2 * q2;
                col = (col < 0) ? 0 : ((col > 190) ? 190 : col);
                xr[u][kt][q2] = *(const float2*)(src + col);
            }
        }
    }

    for (int it = 0; it < ITERS; ++it) {
        // ---- convert prefetched X to f16 frags with validity masks ----
        f16x8 Xf[2][2];   // lane holds X[u][t=chL][f=kt*32+lg*8+q]
        #pragma unroll
        for (int u = 0; u < 2; ++u)
            #pragma unroll
            for (int kt = 0; kt < 2; ++kt) {
                const int rr = r0A[u] + kt * 4 + lg;
                const bool rko = (rr >= 0) && (rr < 192);
                f16x8 v;
                #pragma unroll
                for (int q2 = 0; q2 < 4; ++q2) {
                    const int col = c0A[u] + 2 * q2;
                    const bool ok = rko && (col >= 0) && (col <= 190);
                    v[2 * q2]     = ok ? (f16)xr[u][kt][q2].x : (f16)0.f;
                    v[2 * q2 + 1] = ok ? (f16)xr[u][kt][q2].y : (f16)0.f;
                }
                Xf[u][kt] = v;
            }

        // ---- Phase 1: Q (regs), K,V -> packed LDS; pinned weight clusters ----
        const int wrow = chL * 64 + lg * 8;
        f16x8 wqf[4][2], wkf[4][2];
        #pragma unroll
        for (int h = 0; h < 4; ++h) {
            const int row = (h * 16 + lr) * 64 + lg * 8;
            wqf[h][0] = *(const f16x8*)&wh[row];
            wqf[h][1] = *(const f16x8*)&wh[row + 32];
            wkf[h][0] = *(const f16x8*)&wh[4096 + row];
            wkf[h][1] = *(const f16x8*)&wh[4096 + row + 32];
        }
        __builtin_amdgcn_sched_barrier(0);   // wq/wk issued first
        (void)wrow;

        f16x4 Qf[2][4];   // lane holds Q^T[d=h*16+lg*4+rg][q=lr] (scaled, log2)
        f16x8 wvf[4][2];
        #pragma unroll
        for (int h = 0; h < 4; ++h) {
            const int row = (h * 16 + lr) * 64 + lg * 8;
            wvf[h][0] = *(const f16x8*)&wh[8192 + row];
            wvf[h][1] = *(const f16x8*)&wh[8192 + row + 32];
        }
        #pragma unroll
        for (int h = 0; h < 4; ++h)
            #pragma unroll
            for (int u = 0; u < 2; ++u) {
                f32x4 a = Z;
                a = MFMA32(wqf[h][0], Xf[u][0], a);
                a = MFMA32(wqf[h][1], Xf[u][1], a);
                Qf[u][h] = pack4(a);
            }
        #pragma unroll
        for (int dj = 0; dj < 4; ++dj)
            #pragma unroll
            for (int u = 0; u < 2; ++u) {
                f32x4 a = Z;
                a = MFMA32(wkf[dj][0], Xf[u][0], a);
                a = MFMA32(wkf[dj][1], Xf[u][1], a);
                // C[d=dj*16+lg*4+rg][key=wv*16+lr] -> Kp[(d>>2)][key][d&3]
                *(f16x4*)&Kp[u][(((dj * 4 + lg) * 64) + wv_ * 16 + lr) * 4] = pack4(a);
            }
        #pragma unroll
        for (int dt = 0; dt < 4; ++dt)
            #pragma unroll
            for (int u = 0; u < 2; ++u) {
                f32x4 a = Z;
                a = MFMA32(Xf[u][0], wvf[dt][0], a);
                a = MFMA32(Xf[u][1], wvf[dt][1], a);
                // C[key=wv*16+lg*4+rg][d=dt*16+lr] -> Vp[(key>>2)][d][key&3]
                *(f16x4*)&Vp[u][(((wv_ * 4 + lg) * 64) + dt * 16 + lr) * 4] = pack4(a);
            }
        __syncthreads();

        // ---- Phase 2+3: per head, S^T -> softmax -> PV, pairwise interleaved ----
        f16x4 Of[2][4];   // lane holds O^T[d=h*16+lg*4+rg][q=lr]
        #pragma unroll
        for (int h = 0; h < 4; ++h) {
            f16x4 kf[2][4], vfr[2][4];
            #pragma unroll
            for (int u = 0; u < 2; ++u)
                #pragma unroll
                for (int kt = 0; kt < 4; ++kt) {
                    kf[u][kt]  = *(const f16x4*)&Kp[u][(((h * 4 + lg) * 64) + kt * 16 + lr) * 4];
                    vfr[u][kt] = *(const f16x4*)&Vp[u][(((kt * 4 + lg) * 64) + h * 16 + lr) * 4];
                }

            f32x4 s[2][4];
            #pragma unroll
            for (int u = 0; u < 2; ++u)
                #pragma unroll
                for (int kt = 0; kt < 4; ++kt)
                    s[u][kt] = MFMA16(kf[u][kt], Qf[u][h], Z);   // S^T[key][q] (log2)

            float mx[2], sum[2], rs[2];
            #pragma unroll
            for (int u = 0; u < 2; ++u) {
                float m = s[u][0][0];
                #pragma unroll
                for (int kt = 0; kt < 4; ++kt)
                    #pragma unroll
                    for (int i = 0; i < 4; ++i) m = fmaxf(m, s[u][kt][i]);
                mx[u] = m;
            }
            #pragma unroll
            for (int u = 0; u < 2; ++u) mx[u] = fmaxf(mx[u], __shfl_xor(mx[u], 16, 64));
            #pragma unroll
            for (int u = 0; u < 2; ++u) mx[u] = fmaxf(mx[u], __shfl_xor(mx[u], 32, 64));

            #pragma unroll
            for (int u = 0; u < 2; ++u) {
                float acc = 0.f;
                #pragma unroll
                for (int kt = 0; kt < 4; ++kt)
                    #pragma unroll
                    for (int i = 0; i < 4; ++i) {
                        const float e = __builtin_amdgcn_exp2f(s[u][kt][i] - mx[u]);
                        s[u][kt][i] = e;
                        acc += e;
                    }
                sum[u] = acc;
            }
            #pragma unroll
            for (int u = 0; u < 2; ++u) sum[u] += __shfl_xor(sum[u], 16, 64);
            #pragma unroll
            for (int u = 0; u < 2; ++u) sum[u] += __shfl_xor(sum[u], 32, 64);
            #pragma unroll
            for (int u = 0; u < 2; ++u) rs[u] = __builtin_amdgcn_rcpf(sum[u]);

            #pragma unroll
            for (int u = 0; u < 2; ++u) {
                f16x4 pf[4];   // P[q=lr][key=kt*16+lg*4+i]
                #pragma unroll
                for (int kt = 0; kt < 4; ++kt)
                    #pragma unroll
                    for (int i = 0; i < 4; ++i) pf[kt][i] = (f16)(s[u][kt][i] * rs[u]);
                f32x4 o = Z;
                #pragma unroll
                for (int kt = 0; kt < 4; ++kt)
                    o = MFMA16(vfr[u][kt], pf[kt], o);      // O^T[d][q] accumulate
                Of[u][h] = pack4(o);
            }
        }

        // ---- prefetch next iteration's X (covered by phase 4 + barrier) ----
        int bN[2], jbN[2], r0N[2], c0N[2];
        if (it < ITERS - 1) {
            calc_coords(base + it + 1, bN, jbN, r0N, c0N);
            #pragma unroll
            for (int u = 0; u < 2; ++u) {
                const float* xb = x + ((size_t)(bN[u] * 64 + chL) * 192) * 192;
                #pragma unroll
                for (int kt = 0; kt < 2; ++kt) {
                    const int rr = r0N[u] + kt * 4 + lg;
                    const int rc = (rr >= 0 && rr < 192) ? rr : 0;
                    const float* src = xb + (size_t)rc * 192;
                    #pragma unroll
                    for (int q2 = 0; q2 < 4; ++q2) {
                        int col = c0N[u] + 2 * q2;
                        col = (col < 0) ? 0 : ((col > 190) ? 190 : col);
                        xr[u][kt][q2] = *(const float2*)(src + col);
                    }
                }
            }
        }
        __builtin_amdgcn_sched_barrier(0);   // keep prefetch above phase 4

        // ---- Phase 4: Y^T = Wp * O^T ; all 16 Wp frags batched ----
        const f16* whp = wh + 3 * 4096;
        f16x4 wa[4][4];
        #pragma unroll
        for (int ct = 0; ct < 4; ++ct)
            #pragma unroll
            for (int dt = 0; dt < 4; ++dt)
                wa[ct][dt] = *(const f16x4*)&whp[(ct * 16 + lr) * 64 + dt * 16 + lg * 4];

        #pragma unroll
        for (int ct = 0; ct < 4; ++ct) {
            const int pi  = ct * 2 + (lg >> 1);  // cs=ct*16+lg*4+rg -> pi, pj=(lg&1)*4+rg
            const int pjh = lg & 1;

            #pragma unroll
            for (int u = 0; u < 2; ++u) {
                f32x4 y = Z;
                #pragma unroll
                for (int dt = 0; dt < 4; ++dt)
                    y = MFMA16(wa[ct][dt], Of[u][dt], y);
                // lane holds Y[cs=ct*16+lg*4+rg][q=lr]; token q=lr -> channel
                const int ch = bA[u] * 64 + chL;
                const int hh = r0A[u] + pi;
                if (USE_PLANES) {
                    if (hh >= 0 && hh < 192) {
                        const int p = (pi >> 2) * 2 + pjh;
                        const size_t off = ((size_t)ch * 192 + hh) * 196 + 4 * (jbA[u] + pjh);
                        *(f16x4*)(planes + (size_t)p * PLELEM + off) = pack4(y);
                    }
                } else {
                    if (hh >= 0 && hh < 192) {
                        const float chc = (hh >= 2 && hh <= 189) ? 2.f : 1.f;
                        float* op = out + ((size_t)ch * 192 + hh) * 192;
                        #pragma unroll
                        for (int rg = 0; rg < 4; ++rg) {
                            const int ww = c0A[u] + pjh * 4 + rg;
                            if (ww >= 0 && ww < 192) {
                                const float cwc = (ww >= 2 && ww <= 189) ? 2.f : 1.f;
                                atomicAdd(op + ww, y[rg] / (chc * cwc + 1e-6f));
                            }
                        }
                    }
                }
            }
        }
        __syncthreads();   // all LDS reads done before next iteration overwrites

        if (it < ITERS - 1) {
            #pragma unroll
            for (int u = 0; u < 2; ++u) {
                bA[u] = bN[u]; jbA[u] = jbN[u]; r0A[u] = r0N[u]; c0A[u] = c0N[u];
            }
        }
    }
}

// ---- Pass B: dense coalesced fold of the 4 parity planes ----
__global__ __launch_bounds__(256) void fold_kernel(
    const f16* __restrict__ planes, float* __restrict__ out)
{
    const int idx = blockIdx.x * 256 + threadIdx.x;   // 0..9437183
    const int w  = idx % 192;
    const int t  = idx / 192;
    const int h  = t % 192;
    const int bc = t / 192;
    const bool vlh = (h <= 189), vhh = (h >= 2);
    const bool vlw = (w <= 189), vhw = (w >= 2);
    const size_t base = ((size_t)bc * 192 + h) * 196 + (w + 2);
    float s = 0.f;
    if (vlh && vlw) s += (float)planes[0 * (size_t)PLELEM + base];
    if (vlh && vhw) s += (float)planes[1 * (size_t)PLELEM + base];
    if (vhh && vlw) s += (float)planes[2 * (size_t)PLELEM + base];
    if (vhh && vhw) s += (float)planes[3 * (size_t)PLELEM + base];
    const float cnt = (float)(((int)vlh + (int)vhh) * ((int)vlw + (int)vhw));
    out[idx] = s / (cnt + 1e-6f);
}

extern "C" void kernel_launch(void* const* d_in, const int* in_sizes, int n_in,
                              void* d_out, int out_size, void* d_ws, size_t ws_size,
                              hipStream_t stream)
{
    const float* x  = (const float*)d_in[0];
    const float* wq = (const float*)d_in[1];
    const float* wk = (const float*)d_in[2];
    const float* wv = (const float*)d_in[3];
    const float* wp = (const float*)d_in[4];
    float* out = (float*)d_out;
    f16* wh = (f16*)d_ws;

    wcvt_kernel<<<64, 256, 0, stream>>>(wq, wk, wv, wp, wh);

    if (ws_size >= WS_NEED) {
        f16* planes = (f16*)((char*)d_ws + 32768);
        patch_attn_kernel<true><<<GRID, 256, 0, stream>>>(x, wh, planes, out);
        fold_kernel<<<36864, 256, 0, stream>>>(planes, out);
    } else {
        hipMemsetAsync(d_out, 0, (size_t)out_size * sizeof(float), stream);
        patch_attn_kernel<false><<<GRID, 256, 0, stream>>>(x, wh, nullptr, out);
    }
}

// Round 8
// 406.591 us; speedup vs baseline: 1.1711x; 1.1711x over previous
//
#include <hip/hip_runtime.h>

// LocalRefinedAttention round 8 = round 7 persistence + round 6 locality.
// Round 7 post-mortem: strip-mining slot*4+it made CONCURRENT blocks handle
// patches 8-apart -> per-XCD L2 thrash (FETCH 19->560 MB) and partial-line
// eviction on plane stores (WRITE 78->500 MB, ~6x amplification). Fix: iterate
// with stride 144 (= slots/XCD): pid2 = xcd*576 + it*144 + slot, so resident
// blocks always cover 144 consecutive patch-pairs (round-6 locality) while
// keeping startup amortization + cross-iteration X prefetch.
//
// B=4, C=64, H=W=192, PS=8, STRIDE=4, PAD=2, NHEADS=4, head_dim=16.
// token t = channel; feature/spatial s = pi*8+pj; h = 4*ib+pi-2, w = 4*jb+pj-2.
// Parity planes: p = (pi>=4)*2 + (pj>=4); plane[p][b][ch][h][w2=196] at w2=w+2.
// Each (pixel, p) has exactly one writing patch -> no atomics, no memset.

typedef _Float16 f16;
typedef _Float16 f16x4 __attribute__((ext_vector_type(4)));
typedef _Float16 f16x8 __attribute__((ext_vector_type(8)));
typedef float    f32x4 __attribute__((ext_vector_type(4)));

#define NHP 48
#define LPB (NHP * NHP)          // 2304
#define NPATCH (4 * LPB)         // 9216
#define NPID2 (NPATCH / 2)       // 4608 patch-pairs
#define ITERS 4
#define GRID (NPID2 / ITERS)     // 1152 blocks; 144 slots/XCD
#define SLOTS (GRID / 8)         // 144
#define PLELEM (256 * 192 * 196) // f16 elements per parity plane
#define WS_NEED (32768ull + 4ull * PLELEM * 2ull)

#define MFMA32(A, B, C) __builtin_amdgcn_mfma_f32_16x16x32_f16((A), (B), (C), 0, 0, 0)
#define MFMA16(A, B, C) __builtin_amdgcn_mfma_f32_16x16x16f16((A), (B), (C), 0, 0, 0)

static __device__ __forceinline__ f16x4 pack4(f32x4 a) {
    f16x4 r;
    r[0] = (f16)a[0]; r[1] = (f16)a[1]; r[2] = (f16)a[2]; r[3] = (f16)a[3];
    return r;
}

// ---- weights fp32 -> f16 row-major; SCALE*log2(e) folded into Wq ----
__global__ __launch_bounds__(256) void wcvt_kernel(
    const float* __restrict__ wq, const float* __restrict__ wk,
    const float* __restrict__ wv, const float* __restrict__ wp,
    f16* __restrict__ wh)
{
    const int idx = blockIdx.x * 256 + threadIdx.x;   // 0..16383
    const int m = idx >> 12;
    const int r = idx & 4095;
    const float* src = (m == 0) ? wq : (m == 1) ? wk : (m == 2) ? wv : wp;
    const float s = (m == 0) ? 0.36067376022224085f : 1.0f;  // 0.25 * log2(e)
    wh[idx] = (f16)(src[r] * s);
}

static __device__ __forceinline__ void calc_coords(
    int pid2, int* bA, int* jbA, int* r0A, int* c0A)
{
    #pragma unroll
    for (int u = 0; u < 2; ++u) {
        const int pid = pid2 * 2 + u;
        const int b   = pid / LPB;
        const int rem = pid - b * LPB;
        const int ib  = rem / NHP;
        const int jb  = rem - ib * NHP;
        bA[u]  = b;
        jbA[u] = jb;
        r0A[u] = ib * 4 - 2;
        c0A[u] = jb * 4 - 2;
    }
}

template <bool USE_PLANES>
__global__ __launch_bounds__(256, 4) void patch_attn_kernel(
    const float* __restrict__ x, const f16* __restrict__ wh,
    f16* __restrict__ planes, float* __restrict__ out)
{
    // Packed LDS per patch: Kp[d>>2][key][d&3], Vp[key>>2][d][key&3] (8 KB each)
    __shared__ f16 Kp[2][4096];
    __shared__ f16 Vp[2][4096];

    const int tid  = threadIdx.x;
    const int wv_  = tid >> 6;
    const int lane = tid & 63;
    const int lr   = lane & 15;
    const int lg   = lane >> 4;
    const int chL  = wv_ * 16 + lr;          // this thread's token/channel row

    // Persistent mapping with concurrency-order locality: at fixed it, the
    // XCD's 144 resident slots cover 144 CONSECUTIVE pid2.
    const int n    = blockIdx.x;
    const int xcd  = n & 7;
    const int slot = n >> 3;

    const f32x4 Z = (f32x4){0.f, 0.f, 0.f, 0.f};

    int bA[2], jbA[2], r0A[2], c0A[2];
    calc_coords(xcd * (NPID2 / 8) + slot, bA, jbA, r0A, c0A);

    // Pre-loop X load for it=0 (exposed once per block).
    float2 xr[2][2][4];
    #pragma unroll
    for (int u = 0; u < 2; ++u) {
        const float* xb = x + ((size_t)(bA[u] * 64 + chL) * 192) * 192;
        #pragma unroll
        for (int kt = 0; kt < 2; ++kt) {
            const int rr = r0A[u] + kt * 4 + lg;
            const int rc = (rr >= 0 && rr < 192) ? rr : 0;
            const float* src = xb + (size_t)rc * 192;
            #pragma unroll
            for (int q2 = 0; q2 < 4; ++q2) {
                int col = c0A[u] + 2 * q2;
                col = (col < 0) ? 0 : ((col > 190) ? 190 : col);
                xr[u][kt][q2] = *(const float2*)(src + col);
            }
        }
    }

    for (int it = 0; it < ITERS; ++it) {
        // ---- convert prefetched X to f16 frags with validity masks ----
        f16x8 Xf[2][2];   // lane holds X[u][t=chL][f=kt*32+lg*8+q]
        #pragma unroll
        for (int u = 0; u < 2; ++u)
            #pragma unroll
            for (int kt = 0; kt < 2; ++kt) {
                const int rr = r0A[u] + kt * 4 + lg;
                const bool rko = (rr >= 0) && (rr < 192);
                f16x8 v;
                #pragma unroll
                for (int q2 = 0; q2 < 4; ++q2) {
                    const int col = c0A[u] + 2 * q2;
                    const bool ok = rko && (col >= 0) && (col <= 190);
                    v[2 * q2]     = ok ? (f16)xr[u][kt][q2].x : (f16)0.f;
                    v[2 * q2 + 1] = ok ? (f16)xr[u][kt][q2].y : (f16)0.f;
                }
                Xf[u][kt] = v;
            }

        // ---- Phase 1: Q (regs), K,V -> packed LDS; pinned weight clusters ----
        f16x8 wqf[4][2], wkf[4][2];
        #pragma unroll
        for (int h = 0; h < 4; ++h) {
            const int row = (h * 16 + lr) * 64 + lg * 8;
            wqf[h][0] = *(const f16x8*)&wh[row];
            wqf[h][1] = *(const f16x8*)&wh[row + 32];
            wkf[h][0] = *(const f16x8*)&wh[4096 + row];
            wkf[h][1] = *(const f16x8*)&wh[4096 + row + 32];
        }
        __builtin_amdgcn_sched_barrier(0);   // wq/wk issued first

        f16x4 Qf[2][4];   // lane holds Q^T[d=h*16+lg*4+rg][q=lr] (scaled, log2)
        f16x8 wvf[4][2];
        #pragma unroll
        for (int h = 0; h < 4; ++h) {
            const int row = (h * 16 + lr) * 64 + lg * 8;
            wvf[h][0] = *(const f16x8*)&wh[8192 + row];
            wvf[h][1] = *(const f16x8*)&wh[8192 + row + 32];
        }
        #pragma unroll
        for (int h = 0; h < 4; ++h)
            #pragma unroll
            for (int u = 0; u < 2; ++u) {
                f32x4 a = Z;
                a = MFMA32(wqf[h][0], Xf[u][0], a);
                a = MFMA32(wqf[h][1], Xf[u][1], a);
                Qf[u][h] = pack4(a);
            }
        #pragma unroll
        for (int dj = 0; dj < 4; ++dj)
            #pragma unroll
            for (int u = 0; u < 2; ++u) {
                f32x4 a = Z;
                a = MFMA32(wkf[dj][0], Xf[u][0], a);
                a = MFMA32(wkf[dj][1], Xf[u][1], a);
                // C[d=dj*16+lg*4+rg][key=wv*16+lr] -> Kp[(d>>2)][key][d&3]
                *(f16x4*)&Kp[u][(((dj * 4 + lg) * 64) + wv_ * 16 + lr) * 4] = pack4(a);
            }
        #pragma unroll
        for (int dt = 0; dt < 4; ++dt)
            #pragma unroll
            for (int u = 0; u < 2; ++u) {
                f32x4 a = Z;
                a = MFMA32(Xf[u][0], wvf[dt][0], a);
                a = MFMA32(Xf[u][1], wvf[dt][1], a);
                // C[key=wv*16+lg*4+rg][d=dt*16+lr] -> Vp[(key>>2)][d][key&3]
                *(f16x4*)&Vp[u][(((wv_ * 4 + lg) * 64) + dt * 16 + lr) * 4] = pack4(a);
            }
        __syncthreads();

        // ---- Phase 2+3: per head, S^T -> softmax -> PV, pairwise interleaved ----
        f16x4 Of[2][4];   // lane holds O^T[d=h*16+lg*4+rg][q=lr]
        #pragma unroll
        for (int h = 0; h < 4; ++h) {
            f16x4 kf[2][4], vfr[2][4];
            #pragma unroll
            for (int u = 0; u < 2; ++u)
                #pragma unroll
                for (int kt = 0; kt < 4; ++kt) {
                    kf[u][kt]  = *(const f16x4*)&Kp[u][(((h * 4 + lg) * 64) + kt * 16 + lr) * 4];
                    vfr[u][kt] = *(const f16x4*)&Vp[u][(((kt * 4 + lg) * 64) + h * 16 + lr) * 4];
                }

            f32x4 s[2][4];
            #pragma unroll
            for (int u = 0; u < 2; ++u)
                #pragma unroll
                for (int kt = 0; kt < 4; ++kt)
                    s[u][kt] = MFMA16(kf[u][kt], Qf[u][h], Z);   // S^T[key][q] (log2)

            float mx[2], sum[2], rs[2];
            #pragma unroll
            for (int u = 0; u < 2; ++u) {
                float m = s[u][0][0];
                #pragma unroll
                for (int kt = 0; kt < 4; ++kt)
                    #pragma unroll
                    for (int i = 0; i < 4; ++i) m = fmaxf(m, s[u][kt][i]);
                mx[u] = m;
            }
            #pragma unroll
            for (int u = 0; u < 2; ++u) mx[u] = fmaxf(mx[u], __shfl_xor(mx[u], 16, 64));
            #pragma unroll
            for (int u = 0; u < 2; ++u) mx[u] = fmaxf(mx[u], __shfl_xor(mx[u], 32, 64));

            #pragma unroll
            for (int u = 0; u < 2; ++u) {
                float acc = 0.f;
                #pragma unroll
                for (int kt = 0; kt < 4; ++kt)
                    #pragma unroll
                    for (int i = 0; i < 4; ++i) {
                        const float e = __builtin_amdgcn_exp2f(s[u][kt][i] - mx[u]);
                        s[u][kt][i] = e;
                        acc += e;
                    }
                sum[u] = acc;
            }
            #pragma unroll
            for (int u = 0; u < 2; ++u) sum[u] += __shfl_xor(sum[u], 16, 64);
            #pragma unroll
            for (int u = 0; u < 2; ++u) sum[u] += __shfl_xor(sum[u], 32, 64);
            #pragma unroll
            for (int u = 0; u < 2; ++u) rs[u] = __builtin_amdgcn_rcpf(sum[u]);

            #pragma unroll
            for (int u = 0; u < 2; ++u) {
                f16x4 pf[4];   // P[q=lr][key=kt*16+lg*4+i]
                #pragma unroll
                for (int kt = 0; kt < 4; ++kt)
                    #pragma unroll
                    for (int i = 0; i < 4; ++i) pf[kt][i] = (f16)(s[u][kt][i] * rs[u]);
                f32x4 o = Z;
                #pragma unroll
                for (int kt = 0; kt < 4; ++kt)
                    o = MFMA16(vfr[u][kt], pf[kt], o);      // O^T[d][q] accumulate
                Of[u][h] = pack4(o);
            }
        }

        // ---- prefetch next iteration's X (covered by phase 4 + barrier) ----
        int bN[2], jbN[2], r0N[2], c0N[2];
        if (it < ITERS - 1) {
            calc_coords(xcd * (NPID2 / 8) + (it + 1) * SLOTS + slot, bN, jbN, r0N, c0N);
            #pragma unroll
            for (int u = 0; u < 2; ++u) {
                const float* xb = x + ((size_t)(bN[u] * 64 + chL) * 192) * 192;
                #pragma unroll
                for (int kt = 0; kt < 2; ++kt) {
                    const int rr = r0N[u] + kt * 4 + lg;
                    const int rc = (rr >= 0 && rr < 192) ? rr : 0;
                    const float* src = xb + (size_t)rc * 192;
                    #pragma unroll
                    for (int q2 = 0; q2 < 4; ++q2) {
                        int col = c0N[u] + 2 * q2;
                        col = (col < 0) ? 0 : ((col > 190) ? 190 : col);
                        xr[u][kt][q2] = *(const float2*)(src + col);
                    }
                }
            }
        }
        __builtin_amdgcn_sched_barrier(0);   // keep prefetch above phase 4

        // ---- Phase 4: Y^T = Wp * O^T ; all 16 Wp frags batched ----
        const f16* whp = wh + 3 * 4096;
        f16x4 wa[4][4];
        #pragma unroll
        for (int ct = 0; ct < 4; ++ct)
            #pragma unroll
            for (int dt = 0; dt < 4; ++dt)
                wa[ct][dt] = *(const f16x4*)&whp[(ct * 16 + lr) * 64 + dt * 16 + lg * 4];

        #pragma unroll
        for (int ct = 0; ct < 4; ++ct) {
            const int pi  = ct * 2 + (lg >> 1);  // cs=ct*16+lg*4+rg -> pi, pj=(lg&1)*4+rg
            const int pjh = lg & 1;

            #pragma unroll
            for (int u = 0; u < 2; ++u) {
                f32x4 y = Z;
                #pragma unroll
                for (int dt = 0; dt < 4; ++dt)
                    y = MFMA16(wa[ct][dt], Of[u][dt], y);
                // lane holds Y[cs=ct*16+lg*4+rg][q=lr]; token q=lr -> channel
                const int ch = bA[u] * 64 + chL;
                const int hh = r0A[u] + pi;
                if (USE_PLANES) {
                    if (hh >= 0 && hh < 192) {
                        const int p = (pi >> 2) * 2 + pjh;
                        const size_t off = ((size_t)ch * 192 + hh) * 196 + 4 * (jbA[u] + pjh);
                        *(f16x4*)(planes + (size_t)p * PLELEM + off) = pack4(y);
                    }
                } else {
                    if (hh >= 0 && hh < 192) {
                        const float chc = (hh >= 2 && hh <= 189) ? 2.f : 1.f;
                        float* op = out + ((size_t)ch * 192 + hh) * 192;
                        #pragma unroll
                        for (int rg = 0; rg < 4; ++rg) {
                            const int ww = c0A[u] + pjh * 4 + rg;
                            if (ww >= 0 && ww < 192) {
                                const float cwc = (ww >= 2 && ww <= 189) ? 2.f : 1.f;
                                atomicAdd(op + ww, y[rg] / (chc * cwc + 1e-6f));
                            }
                        }
                    }
                }
            }
        }
        __syncthreads();   // all LDS reads done before next iteration overwrites

        if (it < ITERS - 1) {
            #pragma unroll
            for (int u = 0; u < 2; ++u) {
                bA[u] = bN[u]; jbA[u] = jbN[u]; r0A[u] = r0N[u]; c0A[u] = c0N[u];
            }
        }
    }
}

// ---- Pass B: dense coalesced fold of the 4 parity planes ----
__global__ __launch_bounds__(256) void fold_kernel(
    const f16* __restrict__ planes, float* __restrict__ out)
{
    const int idx = blockIdx.x * 256 + threadIdx.x;   // 0..9437183
    const int w  = idx % 192;
    const int t  = idx / 192;
    const int h  = t % 192;
    const int bc = t / 192;
    const bool vlh = (h <= 189), vhh = (h >= 2);
    const bool vlw = (w <= 189), vhw = (w >= 2);
    const size_t base = ((size_t)bc * 192 + h) * 196 + (w + 2);
    float s = 0.f;
    if (vlh && vlw) s += (float)planes[0 * (size_t)PLELEM + base];
    if (vlh && vhw) s += (float)planes[1 * (size_t)PLELEM + base];
    if (vhh && vlw) s += (float)planes[2 * (size_t)PLELEM + base];
    if (vhh && vhw) s += (float)planes[3 * (size_t)PLELEM + base];
    const float cnt = (float)(((int)vlh + (int)vhh) * ((int)vlw + (int)vhw));
    out[idx] = s / (cnt + 1e-6f);
}

extern "C" void kernel_launch(void* const* d_in, const int* in_sizes, int n_in,
                              void* d_out, int out_size, void* d_ws, size_t ws_size,
                              hipStream_t stream)
{
    const float* x  = (const float*)d_in[0];
    const float* wq = (const float*)d_in[1];
    const float* wk = (const float*)d_in[2];
    const float* wv = (const float*)d_in[3];
    const float* wp = (const float*)d_in[4];
    float* out = (float*)d_out;
    f16* wh = (f16*)d_ws;

    wcvt_kernel<<<64, 256, 0, stream>>>(wq, wk, wv, wp, wh);

    if (ws_size >= WS_NEED) {
        f16* planes = (f16*)((char*)d_ws + 32768);
        patch_attn_kernel<true><<<GRID, 256, 0, stream>>>(x, wh, planes, out);
        fold_kernel<<<36864, 256, 0, stream>>>(planes, out);
    } else {
        hipMemsetAsync(d_out, 0, (size_t)out_size * sizeof(float), stream);
        patch_attn_kernel<false><<<GRID, 256, 0, stream>>>(x, wh, nullptr, out);
    }
}

// Round 9
// 154.417 us; speedup vs baseline: 3.0835x; 2.6331x over previous
//
#include <hip/hip_runtime.h>

// LocalRefinedAttention round 9 = round 6 structure (non-persistent, HW
// dispatch order = locality) with 4 patches/block for ILP.
// Round 7/8 post-mortem: persistent blocks desync across iterations ->
// concurrent blocks stop being jb-consecutive -> L2 thrash (FETCH 395-560 MB)
// + partial-line eviction on plane stores (WRITE ~500 MB). Reverted.
// Round 4->5->6 trend: ILP-per-wave beats occupancy for this latency-bound
// kernel (248 -> 186 -> 166 us while occupancy fell 74 -> 30%). So: P=4
// patches/block (same ib row, jb0..jb0+3): weight frags amortize 4x, softmax
// chains interleave 4-way, X row-loads dedupe (20 float2 vs 32), lane-local
// 32B store runs. Grid 2304, LDS 64KB, 2 blocks/CU.
//
// B=4, C=64, H=W=192, PS=8, STRIDE=4, PAD=2, NHEADS=4, head_dim=16.
// token t = channel; feature/spatial s = pi*8+pj; h = 4*ib+pi-2, w = 4*jb+pj-2.
// Parity planes: p = (pi>=4)*2 + (pj>=4); plane[p][b][ch][h][w2=196] at w2=w+2.
// Each (pixel, p) has exactly one writing patch -> no atomics, no memset.

typedef _Float16 f16;
typedef _Float16 f16x2 __attribute__((ext_vector_type(2)));
typedef _Float16 f16x4 __attribute__((ext_vector_type(4)));
typedef _Float16 f16x8 __attribute__((ext_vector_type(8)));
typedef float    f32x4 __attribute__((ext_vector_type(4)));

#define NHP 48
#define LPB (NHP * NHP)          // 2304
#define NPATCH (4 * LPB)         // 9216
#define PBLK 4                   // patches per block (same ib, jb0..jb0+3)
#define NBLK (NPATCH / PBLK)     // 2304 blocks
#define PLELEM (256 * 192 * 196) // f16 elements per parity plane
#define WS_NEED (32768ull + 4ull * PLELEM * 2ull)

#define MFMA32(A, B, C) __builtin_amdgcn_mfma_f32_16x16x32_f16((A), (B), (C), 0, 0, 0)
#define MFMA16(A, B, C) __builtin_amdgcn_mfma_f32_16x16x16f16((A), (B), (C), 0, 0, 0)

static __device__ __forceinline__ f16x4 pack4(f32x4 a) {
    f16x4 r;
    r[0] = (f16)a[0]; r[1] = (f16)a[1]; r[2] = (f16)a[2]; r[3] = (f16)a[3];
    return r;
}

// ---- weights fp32 -> f16 row-major; SCALE*log2(e) folded into Wq ----
__global__ __launch_bounds__(256) void wcvt_kernel(
    const float* __restrict__ wq, const float* __restrict__ wk,
    const float* __restrict__ wv, const float* __restrict__ wp,
    f16* __restrict__ wh)
{
    const int idx = blockIdx.x * 256 + threadIdx.x;   // 0..16383
    const int m = idx >> 12;
    const int r = idx & 4095;
    const float* src = (m == 0) ? wq : (m == 1) ? wk : (m == 2) ? wv : wp;
    const float s = (m == 0) ? 0.36067376022224085f : 1.0f;  // 0.25 * log2(e)
    wh[idx] = (f16)(src[r] * s);
}

template <bool USE_PLANES>
__global__ __launch_bounds__(256, 2) void patch_attn_kernel(
    const float* __restrict__ x, const f16* __restrict__ wh,
    f16* __restrict__ planes, float* __restrict__ out)
{
    // Packed LDS per patch: Kp[d>>2][key][d&3], Vp[key>>2][d][key&3] (8 KB each)
    __shared__ f16 Kp[PBLK][4096];
    __shared__ f16 Vp[PBLK][4096];

    const int tid  = threadIdx.x;
    const int wv_  = tid >> 6;
    const int lane = tid & 63;
    const int lr   = lane & 15;
    const int lg   = lane >> 4;
    const int chL  = wv_ * 16 + lr;          // this thread's token/channel row

    // XCD-bijective swizzle; consecutive same-XCD blocks = consecutive
    // 4-patch groups (HW dispatch order preserves jb-adjacency of
    // concurrently-running blocks -> L2 read reuse + full-line plane writes).
    const int n   = blockIdx.x;
    const int q   = (n & 7) * (NBLK / 8) + (n >> 3);
    const int pid0 = q * PBLK;
    const int b   = pid0 / LPB;
    const int rem = pid0 - b * LPB;
    const int ib  = rem / NHP;
    const int jb0 = rem - ib * NHP;          // block patches: jb0..jb0+3
    const int r0  = ib * 4 - 2;              // shared rows (same ib for all 4)
    const int c00 = jb0 * 4 - 2;             // patch u starts at c00 + 4u

    const f32x4 Z = (f32x4){0.f, 0.f, 0.f, 0.f};

    // ======== load cluster: X rows (deduped) + Wq/Wk fragments ========
    // Patch u needs floats c00+4u .. c00+4u+7 of each row; union = c00..c00+19
    // = 10 aligned float2 pairs; patch u uses pairs 2u..2u+3.
    float2 xr[2][10];
    {
        const float* xb = x + ((size_t)(b * 64 + chL) * 192) * 192;
        #pragma unroll
        for (int kt = 0; kt < 2; ++kt) {
            const int rr = r0 + kt * 4 + lg;
            const int rc = (rr >= 0 && rr < 192) ? rr : 0;
            const float* src = xb + (size_t)rc * 192;
            #pragma unroll
            for (int j = 0; j < 10; ++j) {
                int cc = c00 + 2 * j;
                cc = (cc < 0) ? 0 : ((cc > 190) ? 190 : cc);
                xr[kt][j] = *(const float2*)(src + cc);
            }
        }
    }
    f16x8 wqf[4][2], wkf[4][2];
    #pragma unroll
    for (int h = 0; h < 4; ++h) {
        const int row = (h * 16 + lr) * 64 + lg * 8;
        wqf[h][0] = *(const f16x8*)&wh[row];
        wqf[h][1] = *(const f16x8*)&wh[row + 32];
        wkf[h][0] = *(const f16x8*)&wh[4096 + row];
        wkf[h][1] = *(const f16x8*)&wh[4096 + row + 32];
    }
    __builtin_amdgcn_sched_barrier(0);   // keep the cluster together

    // ---- convert the 20 pairs once (shared masks), assemble per-patch frags
    f16x2 ht[2][10];
    #pragma unroll
    for (int kt = 0; kt < 2; ++kt) {
        const int rr = r0 + kt * 4 + lg;
        const bool rko = (rr >= 0) && (rr < 192);
        #pragma unroll
        for (int j = 0; j < 10; ++j) {
            const int cc = c00 + 2 * j;
            const bool ok = rko && (cc >= 0) && (cc <= 190);
            ht[kt][j][0] = ok ? (f16)xr[kt][j].x : (f16)0.f;
            ht[kt][j][1] = ok ? (f16)xr[kt][j].y : (f16)0.f;
        }
    }
    f16x8 Xf[PBLK][2];   // lane holds X[u][t=chL][f=kt*32+lg*8+qq]
    #pragma unroll
    for (int u = 0; u < PBLK; ++u)
        #pragma unroll
        for (int kt = 0; kt < 2; ++kt) {
            f16x8 v;
            #pragma unroll
            for (int j = 0; j < 4; ++j) {
                v[2 * j]     = ht[kt][2 * u + j][0];
                v[2 * j + 1] = ht[kt][2 * u + j][1];
            }
            Xf[u][kt] = v;
        }

    // ---- Phase 1: Q (regs), K,V -> packed LDS; weight frags feed 4 patches ----
    f16x4 Qf[PBLK][4];   // lane holds Q^T[d=h*16+lg*4+rg][q=lr] (scaled, log2)
    f16x8 wvf[4][2];
    #pragma unroll
    for (int h = 0; h < 4; ++h) {
        const int row = (h * 16 + lr) * 64 + lg * 8;
        wvf[h][0] = *(const f16x8*)&wh[8192 + row];
        wvf[h][1] = *(const f16x8*)&wh[8192 + row + 32];
    }
    #pragma unroll
    for (int h = 0; h < 4; ++h)
        #pragma unroll
        for (int u = 0; u < PBLK; ++u) {
            f32x4 a = Z;
            a = MFMA32(wqf[h][0], Xf[u][0], a);
            a = MFMA32(wqf[h][1], Xf[u][1], a);
            Qf[u][h] = pack4(a);
        }
    #pragma unroll
    for (int dj = 0; dj < 4; ++dj)
        #pragma unroll
        for (int u = 0; u < PBLK; ++u) {
            f32x4 a = Z;
            a = MFMA32(wkf[dj][0], Xf[u][0], a);
            a = MFMA32(wkf[dj][1], Xf[u][1], a);
            // C[d=dj*16+lg*4+rg][key=wv*16+lr] -> Kp[(d>>2)][key][d&3]
            *(f16x4*)&Kp[u][(((dj * 4 + lg) * 64) + wv_ * 16 + lr) * 4] = pack4(a);
        }
    #pragma unroll
    for (int dt = 0; dt < 4; ++dt)
        #pragma unroll
        for (int u = 0; u < PBLK; ++u) {
            f32x4 a = Z;
            a = MFMA32(Xf[u][0], wvf[dt][0], a);
            a = MFMA32(Xf[u][1], wvf[dt][1], a);
            // C[key=wv*16+lg*4+rg][d=dt*16+lr] -> Vp[(key>>2)][d][key&3]
            *(f16x4*)&Vp[u][(((wv_ * 4 + lg) * 64) + dt * 16 + lr) * 4] = pack4(a);
        }
    __syncthreads();

    // ---- Phase 2+3: per head, S^T -> softmax -> PV; pairs of patches ----
    f16x4 Of[PBLK][4];   // lane holds O^T[d=h*16+lg*4+rg][q=lr]
    #pragma unroll
    for (int h = 0; h < 4; ++h) {
        #pragma unroll
        for (int up = 0; up < PBLK / 2; ++up) {
            f16x4 kf[2][4], vfr[2][4];
            #pragma unroll
            for (int v = 0; v < 2; ++v) {
                const int u = up * 2 + v;
                #pragma unroll
                for (int kt = 0; kt < 4; ++kt) {
                    kf[v][kt]  = *(const f16x4*)&Kp[u][(((h * 4 + lg) * 64) + kt * 16 + lr) * 4];
                    vfr[v][kt] = *(const f16x4*)&Vp[u][(((kt * 4 + lg) * 64) + h * 16 + lr) * 4];
                }
            }

            f32x4 s[2][4];
            #pragma unroll
            for (int v = 0; v < 2; ++v)
                #pragma unroll
                for (int kt = 0; kt < 4; ++kt)
                    s[v][kt] = MFMA16(kf[v][kt], Qf[up * 2 + v][h], Z);  // S^T (log2)

            float mx[2], sum[2], rs[2];
            #pragma unroll
            for (int v = 0; v < 2; ++v) {
                float m = s[v][0][0];
                #pragma unroll
                for (int kt = 0; kt < 4; ++kt)
                    #pragma unroll
                    for (int i = 0; i < 4; ++i) m = fmaxf(m, s[v][kt][i]);
                mx[v] = m;
            }
            #pragma unroll
            for (int v = 0; v < 2; ++v) mx[v] = fmaxf(mx[v], __shfl_xor(mx[v], 16, 64));
            #pragma unroll
            for (int v = 0; v < 2; ++v) mx[v] = fmaxf(mx[v], __shfl_xor(mx[v], 32, 64));

            #pragma unroll
            for (int v = 0; v < 2; ++v) {
                float acc = 0.f;
                #pragma unroll
                for (int kt = 0; kt < 4; ++kt)
                    #pragma unroll
                    for (int i = 0; i < 4; ++i) {
                        const float e = __builtin_amdgcn_exp2f(s[v][kt][i] - mx[v]);
                        s[v][kt][i] = e;
                        acc += e;
                    }
                sum[v] = acc;
            }
            #pragma unroll
            for (int v = 0; v < 2; ++v) sum[v] += __shfl_xor(sum[v], 16, 64);
            #pragma unroll
            for (int v = 0; v < 2; ++v) sum[v] += __shfl_xor(sum[v], 32, 64);
            #pragma unroll
            for (int v = 0; v < 2; ++v) rs[v] = __builtin_amdgcn_rcpf(sum[v]);

            #pragma unroll
            for (int v = 0; v < 2; ++v) {
                f16x4 pf[4];   // P[q=lr][key=kt*16+lg*4+i]
                #pragma unroll
                for (int kt = 0; kt < 4; ++kt)
                    #pragma unroll
                    for (int i = 0; i < 4; ++i) pf[kt][i] = (f16)(s[v][kt][i] * rs[v]);
                f32x4 o = Z;
                #pragma unroll
                for (int kt = 0; kt < 4; ++kt)
                    o = MFMA16(vfr[v][kt], pf[kt], o);      // O^T[d][q] accumulate
                Of[up * 2 + v][h] = pack4(o);
            }
        }
    }

    // ---- Phase 4: Y^T = Wp * O^T ; wa frags feed all 4 patches ----
    const f16* whp = wh + 3 * 4096;
    f16x4 wa[4][4];
    #pragma unroll
    for (int ct = 0; ct < 4; ++ct)
        #pragma unroll
        for (int dt = 0; dt < 4; ++dt)
            wa[ct][dt] = *(const f16x4*)&whp[(ct * 16 + lr) * 64 + dt * 16 + lg * 4];

    const int ch = b * 64 + chL;             // output channel (with batch)
    #pragma unroll
    for (int ct = 0; ct < 4; ++ct) {
        const int pi  = ct * 2 + (lg >> 1);  // cs=ct*16+lg*4+rg -> pi, pj=(lg&1)*4+rg
        const int pjh = lg & 1;
        const int hh  = r0 + pi;             // shared by all 4 patches (same ib)

        #pragma unroll
        for (int u = 0; u < PBLK; ++u) {
            f32x4 y = Z;
            #pragma unroll
            for (int dt = 0; dt < 4; ++dt)
                y = MFMA16(wa[ct][dt], Of[u][dt], y);
            // lane holds Y[cs=ct*16+lg*4+rg][q=lr]; consecutive u -> +8B runs
            if (USE_PLANES) {
                if (hh >= 0 && hh < 192) {
                    const int p = (pi >> 2) * 2 + pjh;
                    const size_t off = ((size_t)ch * 192 + hh) * 196 + 4 * (jb0 + u + pjh);
                    *(f16x4*)(planes + (size_t)p * PLELEM + off) = pack4(y);
                }
            } else {
                if (hh >= 0 && hh < 192) {
                    const float chc = (hh >= 2 && hh <= 189) ? 2.f : 1.f;
                    float* op = out + ((size_t)ch * 192 + hh) * 192;
                    const int c0u = c00 + 4 * u;
                    #pragma unroll
                    for (int rg = 0; rg < 4; ++rg) {
                        const int ww = c0u + pjh * 4 + rg;
                        if (ww >= 0 && ww < 192) {
                            const float cwc = (ww >= 2 && ww <= 189) ? 2.f : 1.f;
                            atomicAdd(op + ww, y[rg] / (chc * cwc + 1e-6f));
                        }
                    }
                }
            }
        }
    }
}

// ---- Pass B: dense coalesced fold of the 4 parity planes ----
__global__ __launch_bounds__(256) void fold_kernel(
    const f16* __restrict__ planes, float* __restrict__ out)
{
    const int idx = blockIdx.x * 256 + threadIdx.x;   // 0..9437183
    const int w  = idx % 192;
    const int t  = idx / 192;
    const int h  = t % 192;
    const int bc = t / 192;
    const bool vlh = (h <= 189), vhh = (h >= 2);
    const bool vlw = (w <= 189), vhw = (w >= 2);
    const size_t base = ((size_t)bc * 192 + h) * 196 + (w + 2);
    float s = 0.f;
    if (vlh && vlw) s += (float)planes[0 * (size_t)PLELEM + base];
    if (vlh && vhw) s += (float)planes[1 * (size_t)PLELEM + base];
    if (vhh && vlw) s += (float)planes[2 * (size_t)PLELEM + base];
    if (vhh && vhw) s += (float)planes[3 * (size_t)PLELEM + base];
    const float cnt = (float)(((int)vlh + (int)vhh) * ((int)vlw + (int)vhw));
    out[idx] = s / (cnt + 1e-6f);
}

extern "C" void kernel_launch(void* const* d_in, const int* in_sizes, int n_in,
                              void* d_out, int out_size, void* d_ws, size_t ws_size,
                              hipStream_t stream)
{
    const float* x  = (const float*)d_in[0];
    const float* wq = (const float*)d_in[1];
    const float* wk = (const float*)d_in[2];
    const float* wv = (const float*)d_in[3];
    const float* wp = (const float*)d_in[4];
    float* out = (float*)d_out;
    f16* wh = (f16*)d_ws;

    wcvt_kernel<<<64, 256, 0, stream>>>(wq, wk, wv, wp, wh);

    if (ws_size >= WS_NEED) {
        f16* planes = (f16*)((char*)d_ws + 32768);
        patch_attn_kernel<true><<<NBLK, 256, 0, stream>>>(x, wh, planes, out);
        fold_kernel<<<36864, 256, 0, stream>>>(planes, out);
    } else {
        hipMemsetAsync(d_out, 0, (size_t)out_size * sizeof(float), stream);
        patch_attn_kernel<false><<<NBLK, 256, 0, stream>>>(x, wh, nullptr, out);
    }
}

// Round 10
// 131.919 us; speedup vs baseline: 3.6094x; 1.1705x over previous
//
#include <hip/hip_runtime.h>

// LocalRefinedAttention round 10: X-exchange / wave-per-head restructure.
// Round 9 post-mortem: P=4 hit the 64KB static LDS limit (2 blocks/CU, 19%
// occupancy); VALU floor ~40us can't be hidden by 8 waves/CU. K+V LDS (16KB/
// patch) exists only to exchange projections across waves. Fix: exchange X
// instead (9.2KB/patch, pitch-72 rows): each wave = one head, computes
// Q/K/V for ALL 64 tokens from LDS X (round-2-verified fragment chains),
// attention in-register, O^T written back over the X buffer (per-patch
// barrier first). LDS 36.9KB -> 4 blocks/CU, ~2.5x occupancy.
//
// B=4, C=64, H=W=192, PS=8, STRIDE=4, PAD=2, NHEADS=4, head_dim=16.
// token t = channel; feature/spatial s = pi*8+pj; h = 4*ib+pi-2, w = 4*jb+pj-2.
// Parity planes: p = (pi>=4)*2 + (pj>=4); plane[p][b][ch][h][w2=196] at w2=w+2.
// Each (pixel, p) has exactly one writing patch -> no atomics, no memset.

typedef _Float16 f16;
typedef _Float16 f16x2 __attribute__((ext_vector_type(2)));
typedef _Float16 f16x4 __attribute__((ext_vector_type(4)));
typedef _Float16 f16x8 __attribute__((ext_vector_type(8)));
typedef float    f32x4 __attribute__((ext_vector_type(4)));

#define NHP 48
#define LPB (NHP * NHP)          // 2304
#define NPATCH (4 * LPB)         // 9216
#define PBLK 4                   // patches per block (same ib, jb0..jb0+3)
#define NBLK (NPATCH / PBLK)     // 2304 blocks
#define LP 72                    // LDS token-row pitch in f16 (144B, 16B-aligned)
#define PLELEM (256 * 192 * 196) // f16 elements per parity plane
#define WS_NEED (32768ull + 4ull * PLELEM * 2ull)

#define MFMA32(A, B, C) __builtin_amdgcn_mfma_f32_16x16x32_f16((A), (B), (C), 0, 0, 0)
#define MFMA16(A, B, C) __builtin_amdgcn_mfma_f32_16x16x16f16((A), (B), (C), 0, 0, 0)

static __device__ __forceinline__ f16x4 pack4(f32x4 a) {
    f16x4 r;
    r[0] = (f16)a[0]; r[1] = (f16)a[1]; r[2] = (f16)a[2]; r[3] = (f16)a[3];
    return r;
}

// ---- weights fp32 -> f16 row-major; SCALE*log2(e) folded into Wq ----
__global__ __launch_bounds__(256) void wcvt_kernel(
    const float* __restrict__ wq, const float* __restrict__ wk,
    const float* __restrict__ wv, const float* __restrict__ wp,
    f16* __restrict__ wh)
{
    const int idx = blockIdx.x * 256 + threadIdx.x;   // 0..16383
    const int m = idx >> 12;
    const int r = idx & 4095;
    const float* src = (m == 0) ? wq : (m == 1) ? wk : (m == 2) ? wv : wp;
    const float s = (m == 0) ? 0.36067376022224085f : 1.0f;  // 0.25 * log2(e)
    wh[idx] = (f16)(src[r] * s);
}

template <bool USE_PLANES>
__global__ __launch_bounds__(256, 4) void patch_attn_kernel(
    const float* __restrict__ x, const f16* __restrict__ wh,
    f16* __restrict__ planes, float* __restrict__ out)
{
    // Xs[u]: X tokens (token-major, pitch 72) -> after per-patch barrier,
    // reused as O (O[tok][d]). 4 x 64 x 72 x 2B = 36864 B.
    __shared__ f16 Xs[PBLK][64 * LP];

    const int tid  = threadIdx.x;
    const int wv_  = tid >> 6;
    const int lane = tid & 63;
    const int lr   = lane & 15;
    const int lg   = lane >> 4;
    const int chL  = wv_ * 16 + lr;          // this thread's token/channel row

    // XCD-bijective swizzle; consecutive same-XCD blocks = consecutive
    // 4-patch groups (HW dispatch order -> jb-adjacent concurrent blocks).
    const int n    = blockIdx.x;
    const int qb   = (n & 7) * (NBLK / 8) + (n >> 3);
    const int pid0 = qb * PBLK;
    const int b    = pid0 / LPB;
    const int rem  = pid0 - b * LPB;
    const int ib   = rem / NHP;
    const int jb0  = rem - ib * NHP;         // block patches: jb0..jb0+3
    const int r0   = ib * 4 - 2;             // shared rows (same ib for all 4)
    const int c00  = jb0 * 4 - 2;            // patch u starts at c00 + 4u

    const f32x4 Z = (f32x4){0.f, 0.f, 0.f, 0.f};

    // ======== X global loads (deduped across the 4 patches) ========
    // Patch u needs floats c00+4u .. c00+4u+7 of each row; union = 10 float2.
    float2 xr[2][10];
    {
        const float* xb = x + ((size_t)(b * 64 + chL) * 192) * 192;
        #pragma unroll
        for (int kt = 0; kt < 2; ++kt) {
            const int rr = r0 + kt * 4 + lg;
            const int rc = (rr >= 0 && rr < 192) ? rr : 0;
            const float* src = xb + (size_t)rc * 192;
            #pragma unroll
            for (int j = 0; j < 10; ++j) {
                int cc = c00 + 2 * j;
                cc = (cc < 0) ? 0 : ((cc > 190) ? 190 : cc);
                xr[kt][j] = *(const float2*)(src + cc);
            }
        }
    }

    // ---- convert once with shared masks ----
    f16x2 ht[2][10];
    #pragma unroll
    for (int kt = 0; kt < 2; ++kt) {
        const int rr = r0 + kt * 4 + lg;
        const bool rko = (rr >= 0) && (rr < 192);
        #pragma unroll
        for (int j = 0; j < 10; ++j) {
            const int cc = c00 + 2 * j;
            const bool ok = rko && (cc >= 0) && (cc <= 190);
            ht[kt][j][0] = ok ? (f16)xr[kt][j].x : (f16)0.f;
            ht[kt][j][1] = ok ? (f16)xr[kt][j].y : (f16)0.f;
        }
    }

    // ---- stage X to LDS: Xs[u][tok=chL][f = kt*32 + lg*8 + q] ----
    #pragma unroll
    for (int u = 0; u < PBLK; ++u)
        #pragma unroll
        for (int kt = 0; kt < 2; ++kt) {
            f16x8 v;
            #pragma unroll
            for (int j = 0; j < 4; ++j) {
                v[2 * j]     = ht[kt][2 * u + j][0];
                v[2 * j + 1] = ht[kt][2 * u + j][1];
            }
            *(f16x8*)&Xs[u][chL * LP + kt * 32 + lg * 8] = v;
        }
    __syncthreads();   // B0: X staged for all 4 patches

    // ======== wave = head h: own-head weight fragments (once) ========
    const int h = wv_;
    const int wrow = (h * 16 + lr) * 64 + lg * 8;
    const f16x8 wqA0 = *(const f16x8*)&wh[wrow];
    const f16x8 wqA1 = *(const f16x8*)&wh[wrow + 32];
    const f16x8 wkA0 = *(const f16x8*)&wh[4096 + wrow];
    const f16x8 wkA1 = *(const f16x8*)&wh[4096 + wrow + 32];
    const f16x8 wvB0 = *(const f16x8*)&wh[8192 + wrow];
    const f16x8 wvB1 = *(const f16x8*)&wh[8192 + wrow + 32];

    // ======== per patch: proj -> barrier -> attention -> O over Xs[u] ========
    #pragma unroll
    for (int u = 0; u < PBLK; ++u) {
        // Q^T/K^T/V C-frags for all 4 token tiles (round-2-verified chains).
        f16x4 Qf[4], Kf[4], Vf[4];
        #pragma unroll
        for (int tt = 0; tt < 4; ++tt) {
            const f16x8 xb0 = *(const f16x8*)&Xs[u][(tt * 16 + lr) * LP + lg * 8];
            const f16x8 xb1 = *(const f16x8*)&Xs[u][(tt * 16 + lr) * LP + 32 + lg * 8];
            f32x4 aq = MFMA32(wqA0, xb0, Z);
            aq = MFMA32(wqA1, xb1, aq);
            Qf[tt] = pack4(aq);                 // Q^T[d=lg*4+rg][tok=lr] (scaled,log2)
            f32x4 ak = MFMA32(wkA0, xb0, Z);
            ak = MFMA32(wkA1, xb1, ak);
            Kf[tt] = pack4(ak);                 // K^T C-frag == A-frag(K)
            f32x4 av = MFMA32(xb0, wvB0, Z);
            av = MFMA32(xb1, wvB1, av);
            Vf[tt] = pack4(av);                 // V C-frag == A-frag(V^T)
        }
        __syncthreads();   // Bu: ALL waves done reading Xs[u] -> O may overwrite

        #pragma unroll
        for (int tj = 0; tj < 4; ++tj) {
            // S^T[key=ti*16+lg*4+rg][q=tj*16+lr] (log2 domain)
            f32x4 s[4];
            #pragma unroll
            for (int ti = 0; ti < 4; ++ti)
                s[ti] = MFMA16(Kf[ti], Qf[tj], Z);

            float mx = s[0][0];
            #pragma unroll
            for (int ti = 0; ti < 4; ++ti)
                #pragma unroll
                for (int i = 0; i < 4; ++i) mx = fmaxf(mx, s[ti][i]);
            mx = fmaxf(mx, __shfl_xor(mx, 16, 64));
            mx = fmaxf(mx, __shfl_xor(mx, 32, 64));

            float sum = 0.f;
            #pragma unroll
            for (int ti = 0; ti < 4; ++ti)
                #pragma unroll
                for (int i = 0; i < 4; ++i) {
                    const float e = __builtin_amdgcn_exp2f(s[ti][i] - mx);
                    s[ti][i] = e;
                    sum += e;
                }
            sum += __shfl_xor(sum, 16, 64);
            sum += __shfl_xor(sum, 32, 64);
            const float rs = __builtin_amdgcn_rcpf(sum);

            f16x4 pf[4];   // P^T[key][q] as B-frags
            #pragma unroll
            for (int ti = 0; ti < 4; ++ti)
                #pragma unroll
                for (int i = 0; i < 4; ++i) pf[ti][i] = (f16)(s[ti][i] * rs);

            f32x4 o = Z;
            #pragma unroll
            for (int ti = 0; ti < 4; ++ti)
                o = MFMA16(Vf[ti], pf[ti], o);  // O^T[d=h*16+lg*4+rg][q=tj*16+lr]

            const f16x4 o4 = pack4(o);
            *(f16x4*)&Xs[u][(tj * 16 + lr) * LP + h * 16 + lg * 4] = o4;
        }
    }
    __syncthreads();   // Bf: all O writes done

    // ======== Phase 4: Y^T = Wp * O^T ; epilogue (round 9 verbatim) ========
    const f16* whp = wh + 3 * 4096;
    f16x4 wa[4][4];
    #pragma unroll
    for (int ct = 0; ct < 4; ++ct)
        #pragma unroll
        for (int dt = 0; dt < 4; ++dt)
            wa[ct][dt] = *(const f16x4*)&whp[(ct * 16 + lr) * 64 + dt * 16 + lg * 4];

    const int ch = b * 64 + chL;             // output channel (with batch)
    #pragma unroll
    for (int u = 0; u < PBLK; ++u) {
        // B-frags of O^T for the wave's own 16 tokens (col = lr -> chL)
        f16x4 OB[4];
        #pragma unroll
        for (int dt = 0; dt < 4; ++dt)
            OB[dt] = *(const f16x4*)&Xs[u][chL * LP + dt * 16 + lg * 4];

        #pragma unroll
        for (int ct = 0; ct < 4; ++ct) {
            f32x4 y = Z;
            #pragma unroll
            for (int dt = 0; dt < 4; ++dt)
                y = MFMA16(wa[ct][dt], OB[dt], y);
            // lane holds Y^T[cs=ct*16+lg*4+rg][tok=lr -> channel chL]
            const int pi  = ct * 2 + (lg >> 1);  // cs -> pi, pj = (lg&1)*4+rg
            const int pjh = lg & 1;
            const int hh  = r0 + pi;
            if (USE_PLANES) {
                if (hh >= 0 && hh < 192) {
                    const int p = (pi >> 2) * 2 + pjh;
                    const size_t off = ((size_t)ch * 192 + hh) * 196 + 4 * (jb0 + u + pjh);
                    *(f16x4*)(planes + (size_t)p * PLELEM + off) = pack4(y);
                }
            } else {
                if (hh >= 0 && hh < 192) {
                    const float chc = (hh >= 2 && hh <= 189) ? 2.f : 1.f;
                    float* op = out + ((size_t)ch * 192 + hh) * 192;
                    const int c0u = c00 + 4 * u;
                    #pragma unroll
                    for (int rg = 0; rg < 4; ++rg) {
                        const int ww = c0u + pjh * 4 + rg;
                        if (ww >= 0 && ww < 192) {
                            const float cwc = (ww >= 2 && ww <= 189) ? 2.f : 1.f;
                            atomicAdd(op + ww, y[rg] / (chc * cwc + 1e-6f));
                        }
                    }
                }
            }
        }
    }
}

// ---- Pass B: dense coalesced fold of the 4 parity planes ----
__global__ __launch_bounds__(256) void fold_kernel(
    const f16* __restrict__ planes, float* __restrict__ out)
{
    const int idx = blockIdx.x * 256 + threadIdx.x;   // 0..9437183
    const int w  = idx % 192;
    const int t  = idx / 192;
    const int h  = t % 192;
    const int bc = t / 192;
    const bool vlh = (h <= 189), vhh = (h >= 2);
    const bool vlw = (w <= 189), vhw = (w >= 2);
    const size_t base = ((size_t)bc * 192 + h) * 196 + (w + 2);
    float s = 0.f;
    if (vlh && vlw) s += (float)planes[0 * (size_t)PLELEM + base];
    if (vlh && vhw) s += (float)planes[1 * (size_t)PLELEM + base];
    if (vhh && vlw) s += (float)planes[2 * (size_t)PLELEM + base];
    if (vhh && vhw) s += (float)planes[3 * (size_t)PLELEM + base];
    const float cnt = (float)(((int)vlh + (int)vhh) * ((int)vlw + (int)vhw));
    out[idx] = s / (cnt + 1e-6f);
}

extern "C" void kernel_launch(void* const* d_in, const int* in_sizes, int n_in,
                              void* d_out, int out_size, void* d_ws, size_t ws_size,
                              hipStream_t stream)
{
    const float* x  = (const float*)d_in[0];
    const float* wq = (const float*)d_in[1];
    const float* wk = (const float*)d_in[2];
    const float* wv = (const float*)d_in[3];
    const float* wp = (const float*)d_in[4];
    float* out = (float*)d_out;
    f16* wh = (f16*)d_ws;

    wcvt_kernel<<<64, 256, 0, stream>>>(wq, wk, wv, wp, wh);

    if (ws_size >= WS_NEED) {
        f16* planes = (f16*)((char*)d_ws + 32768);
        patch_attn_kernel<true><<<NBLK, 256, 0, stream>>>(x, wh, planes, out);
        fold_kernel<<<36864, 256, 0, stream>>>(planes, out);
    } else {
        hipMemsetAsync(d_out, 0, (size_t)out_size * sizeof(float), stream);
        patch_attn_kernel<false><<<NBLK, 256, 0, stream>>>(x, wh, nullptr, out);
    }
}

// Round 11
// 130.292 us; speedup vs baseline: 3.6545x; 1.0125x over previous
//
#include <hip/hip_runtime.h>

// LocalRefinedAttention round 11 = round 10 + {pitch-64 XOR-swizzled LDS,
// ct-outer phase-4 store order}.
// Round 10 post-mortem: (1) pitch-72 staging writes were 8-way bank-conflicted
// (2.36M cycles); (2) u-outer phase-4 spread the 4 stores completing each 64B
// plane line -> partial-line eviction (WRITE 77->122MB); (3) LDS 36.9KB capped
// at 4 blocks/CU. Fix: pitch 64 with XOR swizzle f ^= (tok&7)<<3 applied on
// BOTH write and read sides (stage, proj-read, O-write, OB-read) -> LDS
// 32768B = exactly 5 blocks/CU and conflict-free b128 access; phase 4 back to
// ct-outer/u-inner (round-9 store clustering). VGPR must stay <=64 (8 waves/
// SIMD budget) or the 5th block is forfeit.
//
// B=4, C=64, H=W=192, PS=8, STRIDE=4, PAD=2, NHEADS=4, head_dim=16.
// token t = channel; feature/spatial s = pi*8+pj; h = 4*ib+pi-2, w = 4*jb+pj-2.
// Parity planes: p = (pi>=4)*2 + (pj>=4); plane[p][b][ch][h][w2=196] at w2=w+2.
// Each (pixel, p) has exactly one writing patch -> no atomics, no memset.

typedef _Float16 f16;
typedef _Float16 f16x2 __attribute__((ext_vector_type(2)));
typedef _Float16 f16x4 __attribute__((ext_vector_type(4)));
typedef _Float16 f16x8 __attribute__((ext_vector_type(8)));
typedef float    f32x4 __attribute__((ext_vector_type(4)));

#define NHP 48
#define LPB (NHP * NHP)          // 2304
#define NPATCH (4 * LPB)         // 9216
#define PBLK 4                   // patches per block (same ib, jb0..jb0+3)
#define NBLK (NPATCH / PBLK)     // 2304 blocks
#define PLELEM (256 * 192 * 196) // f16 elements per parity plane
#define WS_NEED (32768ull + 4ull * PLELEM * 2ull)

#define MFMA32(A, B, C) __builtin_amdgcn_mfma_f32_16x16x32_f16((A), (B), (C), 0, 0, 0)
#define MFMA16(A, B, C) __builtin_amdgcn_mfma_f32_16x16x16f16((A), (B), (C), 0, 0, 0)

// XOR-swizzled LDS index: token-major pitch 64 f16; flips f16-index bits 3..5
// by (tok&7) -> spreads the column accesses of a 16-lane group across banks.
// Preserves 16B alignment for f that is a multiple of 8, 8B for multiple of 4.
static __device__ __forceinline__ int XS(int tok, int f) {
    return tok * 64 + (f ^ ((tok & 7) << 3));
}

static __device__ __forceinline__ f16x4 pack4(f32x4 a) {
    f16x4 r;
    r[0] = (f16)a[0]; r[1] = (f16)a[1]; r[2] = (f16)a[2]; r[3] = (f16)a[3];
    return r;
}

// ---- weights fp32 -> f16 row-major; SCALE*log2(e) folded into Wq ----
__global__ __launch_bounds__(256) void wcvt_kernel(
    const float* __restrict__ wq, const float* __restrict__ wk,
    const float* __restrict__ wv, const float* __restrict__ wp,
    f16* __restrict__ wh)
{
    const int idx = blockIdx.x * 256 + threadIdx.x;   // 0..16383
    const int m = idx >> 12;
    const int r = idx & 4095;
    const float* src = (m == 0) ? wq : (m == 1) ? wk : (m == 2) ? wv : wp;
    const float s = (m == 0) ? 0.36067376022224085f : 1.0f;  // 0.25 * log2(e)
    wh[idx] = (f16)(src[r] * s);
}

template <bool USE_PLANES>
__global__ __launch_bounds__(256, 4) void patch_attn_kernel(
    const float* __restrict__ x, const f16* __restrict__ wh,
    f16* __restrict__ planes, float* __restrict__ out)
{
    // Xs[u]: X tokens (swizzled pitch 64) -> after per-patch barrier, reused
    // as O. 4 x 64 x 64 x 2B = 32768 B = exactly 5 blocks/CU.
    __shared__ f16 Xs[PBLK][64 * 64];

    const int tid  = threadIdx.x;
    const int wv_  = tid >> 6;
    const int lane = tid & 63;
    const int lr   = lane & 15;
    const int lg   = lane >> 4;
    const int chL  = wv_ * 16 + lr;          // this thread's token/channel row

    // XCD-bijective swizzle; consecutive same-XCD blocks = consecutive
    // 4-patch groups (HW dispatch order -> jb-adjacent concurrent blocks).
    const int n    = blockIdx.x;
    const int qb   = (n & 7) * (NBLK / 8) + (n >> 3);
    const int pid0 = qb * PBLK;
    const int b    = pid0 / LPB;
    const int rem  = pid0 - b * LPB;
    const int ib   = rem / NHP;
    const int jb0  = rem - ib * NHP;         // block patches: jb0..jb0+3
    const int r0   = ib * 4 - 2;             // shared rows (same ib for all 4)
    const int c00  = jb0 * 4 - 2;            // patch u starts at c00 + 4u

    const f32x4 Z = (f32x4){0.f, 0.f, 0.f, 0.f};

    // ======== X global loads (deduped across the 4 patches) ========
    float2 xr[2][10];
    {
        const float* xb = x + ((size_t)(b * 64 + chL) * 192) * 192;
        #pragma unroll
        for (int kt = 0; kt < 2; ++kt) {
            const int rr = r0 + kt * 4 + lg;
            const int rc = (rr >= 0 && rr < 192) ? rr : 0;
            const float* src = xb + (size_t)rc * 192;
            #pragma unroll
            for (int j = 0; j < 10; ++j) {
                int cc = c00 + 2 * j;
                cc = (cc < 0) ? 0 : ((cc > 190) ? 190 : cc);
                xr[kt][j] = *(const float2*)(src + cc);
            }
        }
    }

    // ---- convert once with shared masks ----
    f16x2 ht[2][10];
    #pragma unroll
    for (int kt = 0; kt < 2; ++kt) {
        const int rr = r0 + kt * 4 + lg;
        const bool rko = (rr >= 0) && (rr < 192);
        #pragma unroll
        for (int j = 0; j < 10; ++j) {
            const int cc = c00 + 2 * j;
            const bool ok = rko && (cc >= 0) && (cc <= 190);
            ht[kt][j][0] = ok ? (f16)xr[kt][j].x : (f16)0.f;
            ht[kt][j][1] = ok ? (f16)xr[kt][j].y : (f16)0.f;
        }
    }

    // ---- stage X to LDS (swizzled): Xs[u][XS(chL, kt*32 + lg*8)] ----
    #pragma unroll
    for (int u = 0; u < PBLK; ++u)
        #pragma unroll
        for (int kt = 0; kt < 2; ++kt) {
            f16x8 v;
            #pragma unroll
            for (int j = 0; j < 4; ++j) {
                v[2 * j]     = ht[kt][2 * u + j][0];
                v[2 * j + 1] = ht[kt][2 * u + j][1];
            }
            *(f16x8*)&Xs[u][XS(chL, kt * 32 + lg * 8)] = v;
        }
    __syncthreads();   // B0: X staged for all 4 patches

    // ======== wave = head h: own-head weight fragments (once) ========
    const int h = wv_;
    const int wrow = (h * 16 + lr) * 64 + lg * 8;
    const f16x8 wqA0 = *(const f16x8*)&wh[wrow];
    const f16x8 wqA1 = *(const f16x8*)&wh[wrow + 32];
    const f16x8 wkA0 = *(const f16x8*)&wh[4096 + wrow];
    const f16x8 wkA1 = *(const f16x8*)&wh[4096 + wrow + 32];
    const f16x8 wvB0 = *(const f16x8*)&wh[8192 + wrow];
    const f16x8 wvB1 = *(const f16x8*)&wh[8192 + wrow + 32];

    // ======== per patch: proj -> barrier -> attention -> O over Xs[u] ========
    #pragma unroll
    for (int u = 0; u < PBLK; ++u) {
        // Q^T/K^T/V C-frags for all 4 token tiles (round-2-verified chains).
        f16x4 Qf[4], Kf[4], Vf[4];
        #pragma unroll
        for (int tt = 0; tt < 4; ++tt) {
            const int tok = tt * 16 + lr;
            const f16x8 xb0 = *(const f16x8*)&Xs[u][XS(tok, lg * 8)];
            const f16x8 xb1 = *(const f16x8*)&Xs[u][XS(tok, 32 + lg * 8)];
            f32x4 aq = MFMA32(wqA0, xb0, Z);
            aq = MFMA32(wqA1, xb1, aq);
            Qf[tt] = pack4(aq);                 // Q^T[d=lg*4+rg][tok=lr] (scaled,log2)
            f32x4 ak = MFMA32(wkA0, xb0, Z);
            ak = MFMA32(wkA1, xb1, ak);
            Kf[tt] = pack4(ak);                 // K^T C-frag == A-frag(K)
            f32x4 av = MFMA32(xb0, wvB0, Z);
            av = MFMA32(xb1, wvB1, av);
            Vf[tt] = pack4(av);                 // V C-frag == A-frag(V^T)
        }
        __syncthreads();   // Bu: ALL waves done reading Xs[u] -> O may overwrite

        #pragma unroll
        for (int tj = 0; tj < 4; ++tj) {
            // S^T[key=ti*16+lg*4+rg][q=tj*16+lr] (log2 domain)
            f32x4 s[4];
            #pragma unroll
            for (int ti = 0; ti < 4; ++ti)
                s[ti] = MFMA16(Kf[ti], Qf[tj], Z);

            float mx = s[0][0];
            #pragma unroll
            for (int ti = 0; ti < 4; ++ti)
                #pragma unroll
                for (int i = 0; i < 4; ++i) mx = fmaxf(mx, s[ti][i]);
            mx = fmaxf(mx, __shfl_xor(mx, 16, 64));
            mx = fmaxf(mx, __shfl_xor(mx, 32, 64));

            float sum = 0.f;
            #pragma unroll
            for (int ti = 0; ti < 4; ++ti)
                #pragma unroll
                for (int i = 0; i < 4; ++i) {
                    const float e = __builtin_amdgcn_exp2f(s[ti][i] - mx);
                    s[ti][i] = e;
                    sum += e;
                }
            sum += __shfl_xor(sum, 16, 64);
            sum += __shfl_xor(sum, 32, 64);
            const float rs = __builtin_amdgcn_rcpf(sum);

            f16x4 pf[4];   // P^T[key][q] as B-frags
            #pragma unroll
            for (int ti = 0; ti < 4; ++ti)
                #pragma unroll
                for (int i = 0; i < 4; ++i) pf[ti][i] = (f16)(s[ti][i] * rs);

            f32x4 o = Z;
            #pragma unroll
            for (int ti = 0; ti < 4; ++ti)
                o = MFMA16(Vf[ti], pf[ti], o);  // O^T[d=h*16+lg*4+rg][q=tj*16+lr]

            const f16x4 o4 = pack4(o);
            *(f16x4*)&Xs[u][XS(tj * 16 + lr, h * 16 + lg * 4)] = o4;
        }
    }
    __syncthreads();   // Bf: all O writes done

    // ======== Phase 4: Y^T = Wp * O^T ; ct-outer for store clustering ========
    const f16* whp = wh + 3 * 4096;
    f16x4 wa[4][4];
    #pragma unroll
    for (int ct = 0; ct < 4; ++ct)
        #pragma unroll
        for (int dt = 0; dt < 4; ++dt)
            wa[ct][dt] = *(const f16x4*)&whp[(ct * 16 + lr) * 64 + dt * 16 + lg * 4];

    const int ch = b * 64 + chL;             // output channel (with batch)
    #pragma unroll
    for (int ct = 0; ct < 4; ++ct) {
        const int pi  = ct * 2 + (lg >> 1);  // cs=ct*16+lg*4+rg -> pi, pj=(lg&1)*4+rg
        const int pjh = lg & 1;
        const int hh  = r0 + pi;             // shared by all 4 patches (same ib)

        #pragma unroll
        for (int u = 0; u < PBLK; ++u) {
            f32x4 y = Z;
            #pragma unroll
            for (int dt = 0; dt < 4; ++dt) {
                const f16x4 ob = *(const f16x4*)&Xs[u][XS(chL, dt * 16 + lg * 4)];
                y = MFMA16(wa[ct][dt], ob, y);
            }
            // lane holds Y^T[cs=ct*16+lg*4+rg][tok=lr -> channel chL];
            // consecutive u at same ct -> adjacent 8B runs complete plane lines.
            if (USE_PLANES) {
                if (hh >= 0 && hh < 192) {
                    const int p = (pi >> 2) * 2 + pjh;
                    const size_t off = ((size_t)ch * 192 + hh) * 196 + 4 * (jb0 + u + pjh);
                    *(f16x4*)(planes + (size_t)p * PLELEM + off) = pack4(y);
                }
            } else {
                if (hh >= 0 && hh < 192) {
                    const float chc = (hh >= 2 && hh <= 189) ? 2.f : 1.f;
                    float* op = out + ((size_t)ch * 192 + hh) * 192;
                    const int c0u = c00 + 4 * u;
                    #pragma unroll
                    for (int rg = 0; rg < 4; ++rg) {
                        const int ww = c0u + pjh * 4 + rg;
                        if (ww >= 0 && ww < 192) {
                            const float cwc = (ww >= 2 && ww <= 189) ? 2.f : 1.f;
                            atomicAdd(op + ww, y[rg] / (chc * cwc + 1e-6f));
                        }
                    }
                }
            }
        }
    }
}

// ---- Pass B: dense coalesced fold of the 4 parity planes ----
__global__ __launch_bounds__(256) void fold_kernel(
    const f16* __restrict__ planes, float* __restrict__ out)
{
    const int idx = blockIdx.x * 256 + threadIdx.x;   // 0..9437183
    const int w  = idx % 192;
    const int t  = idx / 192;
    const int h  = t % 192;
    const int bc = t / 192;
    const bool vlh = (h <= 189), vhh = (h >= 2);
    const bool vlw = (w <= 189), vhw = (w >= 2);
    const size_t base = ((size_t)bc * 192 + h) * 196 + (w + 2);
    float s = 0.f;
    if (vlh && vlw) s += (float)planes[0 * (size_t)PLELEM + base];
    if (vlh && vhw) s += (float)planes[1 * (size_t)PLELEM + base];
    if (vhh && vlw) s += (float)planes[2 * (size_t)PLELEM + base];
    if (vhh && vhw) s += (float)planes[3 * (size_t)PLELEM + base];
    const float cnt = (float)(((int)vlh + (int)vhh) * ((int)vlw + (int)vhw));
    out[idx] = s / (cnt + 1e-6f);
}

extern "C" void kernel_launch(void* const* d_in, const int* in_sizes, int n_in,
                              void* d_out, int out_size, void* d_ws, size_t ws_size,
                              hipStream_t stream)
{
    const float* x  = (const float*)d_in[0];
    const float* wq = (const float*)d_in[1];
    const float* wk = (const float*)d_in[2];
    const float* wv = (const float*)d_in[3];
    const float* wp = (const float*)d_in[4];
    float* out = (float*)d_out;
    f16* wh = (f16*)d_ws;

    wcvt_kernel<<<64, 256, 0, stream>>>(wq, wk, wv, wp, wh);

    if (ws_size >= WS_NEED) {
        f16* planes = (f16*)((char*)d_ws + 32768);
        patch_attn_kernel<true><<<NBLK, 256, 0, stream>>>(x, wh, planes, out);
        fold_kernel<<<36864, 256, 0, stream>>>(planes, out);
    } else {
        hipMemsetAsync(d_out, 0, (size_t)out_size * sizeof(float), stream);
        patch_attn_kernel<false><<<NBLK, 256, 0, stream>>>(x, wh, nullptr, out);
    }
}